// Round 1
// baseline (162.017 us; speedup 1.0000x reference)
//
#include <hip/hip_runtime.h>
#include <hip/hip_bf16.h>
#include <cmath>

// ---------- types ----------
typedef __attribute__((ext_vector_type(8))) short bf16x8;   // 8 bf16 in 4 VGPRs (MFMA A/B frag)
typedef __attribute__((ext_vector_type(4))) float f32x4;    // MFMA C/D frag

__device__ __forceinline__ unsigned short f2bf(float f) {
    union { float f; unsigned int i; } c; c.f = f;
    unsigned int i = c.i;
    unsigned int r = i + 0x7FFF + ((i >> 16) & 1);   // round-to-nearest-even
    return (unsigned short)(r >> 16);
}

// ---------- conversion kernels ----------
__global__ void k_cvt(const float* __restrict__ src, unsigned short* __restrict__ dst, int n4) {
    int i = blockIdx.x * blockDim.x + threadIdx.x;
    if (i < n4) {
        float4 v = reinterpret_cast<const float4*>(src)[i];
        ushort4 o;
        o.x = f2bf(v.x); o.y = f2bf(v.y); o.z = f2bf(v.z); o.w = f2bf(v.w);
        reinterpret_cast<ushort4*>(dst)[i] = o;
    }
}

// Wq/Wk/Wv [H=16][C=1024][S=64] f32  ->  Wt [n=sec*1024+h*64+s][c] bf16 (K-contiguous)
// grid = 3*16*16 blocks (sec, h, c-tile), 256 threads
__global__ void k_cvt_wt(const float* __restrict__ Wq, const float* __restrict__ Wk,
                         const float* __restrict__ Wv, unsigned short* __restrict__ Wt) {
    __shared__ unsigned short lt[64][72];   // [s][c], padded
    int bid = blockIdx.x;
    int ct  = bid & 15;
    int h   = (bid >> 4) & 15;
    int sec = bid >> 8;
    const float* W = (sec == 0) ? Wq : ((sec == 1) ? Wk : Wv);
    int t = threadIdx.x;
    #pragma unroll
    for (int q = 0; q < 4; q++) {
        int id = t + q * 256;          // 0..1023
        int c  = id >> 4;              // 0..63
        int s4 = (id & 15) * 4;        // 0..60
        float4 v = *reinterpret_cast<const float4*>(&W[((size_t)(h * 1024) + (ct * 64 + c)) * 64 + s4]);
        lt[s4 + 0][c] = f2bf(v.x);
        lt[s4 + 1][c] = f2bf(v.y);
        lt[s4 + 2][c] = f2bf(v.z);
        lt[s4 + 3][c] = f2bf(v.w);
    }
    __syncthreads();
    #pragma unroll
    for (int q = 0; q < 2; q++) {
        int id = t + q * 256;          // 0..511
        int s  = id >> 3;              // 0..63
        int c8 = (id & 7) * 8;         // 0..56
        bf16x8 val = *reinterpret_cast<const bf16x8*>(&lt[s][c8]);
        int n = sec * 1024 + h * 64 + s;
        *reinterpret_cast<bf16x8*>(&Wt[(size_t)n * 1024 + ct * 64 + c8]) = val;
    }
}

// ---------- GEMM: C[M][N] = A[M][K] * Bt[N][K]^T ----------
// MODE 0: QKV -> q_nat [m][win], k_nat [m][win], vT [b][h][s][t]
// MODE 1: proj -> out f32 [m][n] + bias
template <int MODE>
__launch_bounds__(256, 2)
__global__ void k_gemm(const unsigned short* __restrict__ A,
                       const unsigned short* __restrict__ Bt,
                       int M, int N, int K,
                       unsigned short* __restrict__ q_nat,
                       unsigned short* __restrict__ k_nat,
                       unsigned short* __restrict__ vT,
                       float* __restrict__ out, const float* __restrict__ bp) {
    __shared__ unsigned short Asm[128][40];   // pad 32->40 (80B rows: 2-way bank, free)
    __shared__ unsigned short Bsm[128][40];
    const int nb = N >> 7;
    int bid = blockIdx.x;
    int n0 = (bid % nb) << 7;
    int m0 = (bid / nb) << 7;
    int t = threadIdx.x;
    int lane = t & 63, w = t >> 6;
    int wr = w >> 1, wc = w & 1;
    int l15 = lane & 15, lg = lane >> 4;

    f32x4 acc[4][4];
    #pragma unroll
    for (int i = 0; i < 4; i++)
        #pragma unroll
        for (int j = 0; j < 4; j++) acc[i][j] = (f32x4){0.f, 0.f, 0.f, 0.f};

    for (int kt = 0; kt < K; kt += 32) {
        #pragma unroll
        for (int q = 0; q < 2; q++) {
            int id = t + q * 256;          // 0..511
            int r  = id >> 2;              // 0..127
            int c8 = (id & 3) << 3;        // 0..24
            *reinterpret_cast<bf16x8*>(&Asm[r][c8]) =
                *reinterpret_cast<const bf16x8*>(&A[(size_t)(m0 + r) * K + kt + c8]);
            *reinterpret_cast<bf16x8*>(&Bsm[r][c8]) =
                *reinterpret_cast<const bf16x8*>(&Bt[(size_t)(n0 + r) * K + kt + c8]);
        }
        __syncthreads();
        bf16x8 af[4], bfrag[4];
        #pragma unroll
        for (int mi = 0; mi < 4; mi++)
            af[mi] = *reinterpret_cast<const bf16x8*>(&Asm[wr * 64 + mi * 16 + l15][lg * 8]);
        #pragma unroll
        for (int nj = 0; nj < 4; nj++)
            bfrag[nj] = *reinterpret_cast<const bf16x8*>(&Bsm[wc * 64 + nj * 16 + l15][lg * 8]);
        #pragma unroll
        for (int mi = 0; mi < 4; mi++)
            #pragma unroll
            for (int nj = 0; nj < 4; nj++)
                acc[mi][nj] = __builtin_amdgcn_mfma_f32_16x16x32_bf16(af[mi], bfrag[nj], acc[mi][nj], 0, 0, 0);
        __syncthreads();
    }

    #pragma unroll
    for (int mi = 0; mi < 4; mi++) {
        #pragma unroll
        for (int nj = 0; nj < 4; nj++) {
            #pragma unroll
            for (int r = 0; r < 4; r++) {
                int m = m0 + wr * 64 + mi * 16 + lg * 4 + r;
                int n = n0 + wc * 64 + nj * 16 + l15;
                float v = acc[mi][nj][r];
                if (MODE == 0) {
                    int sec = n >> 10;
                    int win = n & 1023;
                    if (sec == 0) {
                        q_nat[(size_t)m * 1024 + win] = f2bf(v);
                    } else if (sec == 1) {
                        k_nat[(size_t)m * 1024 + win] = f2bf(v);
                    } else {
                        int b = m >> 11, tt = m & 2047;
                        int h = win >> 6, s = win & 63;
                        vT[(((size_t)(b * 16 + h)) * 64 + s) * 2048 + tt] = f2bf(v);
                    }
                } else {
                    out[(size_t)m * 1024 + n] = v + bp[n];
                }
            }
        }
    }
}

// ---------- flash attention ----------
// grid = B*H*16 = 512 blocks; each block does q-tiles {p, 31-p} (uniform 33 kv-tiles).
// 4 waves, each wave owns 16 q-rows of the 64-row tile. QBLK=KVBLK=64, S=64.
__launch_bounds__(256, 2)
__global__ void k_attn(const unsigned short* __restrict__ q_nat,
                       const unsigned short* __restrict__ k_nat,
                       const unsigned short* __restrict__ vT,
                       unsigned short* __restrict__ y_bf) {
    __shared__ unsigned short Ks[64][72];       // K tile [kv][s], padded
    __shared__ unsigned short Vs[64][72];       // V^T tile [s][kv], padded
    __shared__ unsigned short Ps[4][16][72];    // per-wave P tile [q][kv], padded
    const int T = 2048, H = 16;
    int bid = blockIdx.x;
    int p = bid & 15;
    int h = (bid >> 4) & 15;
    int b = bid >> 8;
    int t = threadIdx.x;
    int lane = t & 63, w = t >> 6;
    int l15 = lane & 15, lg = lane >> 4;

    for (int half = 0; half < 2; half++) {
        int qi = (half == 0) ? p : (31 - p);

        // Q fragments: wave w owns q-rows qi*64 + w*16 .. +16
        bf16x8 qf[2];
        int qrow = qi * 64 + w * 16 + l15;
        #pragma unroll
        for (int kk = 0; kk < 2; kk++)
            qf[kk] = *reinterpret_cast<const bf16x8*>(
                &q_nat[((size_t)(b * T + qrow)) * 1024 + h * 64 + kk * 32 + lg * 8]);

        float mrow[4], ell[4];
        f32x4 acc[4];
        #pragma unroll
        for (int r = 0; r < 4; r++) { mrow[r] = -INFINITY; ell[r] = 0.f; }
        #pragma unroll
        for (int sb = 0; sb < 4; sb++) acc[sb] = (f32x4){0.f, 0.f, 0.f, 0.f};

        for (int j = 0; j <= qi; j++) {
            // stage K, V^T tiles (each 64 rows x 64 cols bf16)
            #pragma unroll
            for (int qq = 0; qq < 2; qq++) {
                int id = t + qq * 256;         // 0..511
                int r  = id >> 3;              // 0..63
                int c8 = (id & 7) << 3;        // 0..56
                *reinterpret_cast<bf16x8*>(&Ks[r][c8]) =
                    *reinterpret_cast<const bf16x8*>(
                        &k_nat[((size_t)(b * T + j * 64 + r)) * 1024 + h * 64 + c8]);
                *reinterpret_cast<bf16x8*>(&Vs[r][c8]) =
                    *reinterpret_cast<const bf16x8*>(
                        &vT[(((size_t)(b * H + h)) * 64 + r) * 2048 + j * 64 + c8]);
            }
            __syncthreads();

            // S = Q K^T  (A = Q rows, B[k][n] = K[cb*16+n][k] from Ks)
            f32x4 sacc[4];
            #pragma unroll
            for (int cb = 0; cb < 4; cb++) {
                sacc[cb] = (f32x4){0.f, 0.f, 0.f, 0.f};
                #pragma unroll
                for (int kk = 0; kk < 2; kk++) {
                    bf16x8 bfr = *reinterpret_cast<const bf16x8*>(&Ks[cb * 16 + l15][kk * 32 + lg * 8]);
                    sacc[cb] = __builtin_amdgcn_mfma_f32_16x16x32_bf16(qf[kk], bfr, sacc[cb], 0, 0, 0);
                }
            }

            // online softmax
            float pv[4][4];   // [cb][r]
            float tmax[4];
            bool diag = (j == qi);
            #pragma unroll
            for (int r = 0; r < 4; r++) tmax[r] = -INFINITY;
            #pragma unroll
            for (int cb = 0; cb < 4; cb++) {
                #pragma unroll
                for (int r = 0; r < 4; r++) {
                    float s = sacc[cb][r] * 0.125f;
                    if (diag) {
                        int kv = cb * 16 + l15;
                        int qq = w * 16 + lg * 4 + r;
                        if (kv > qq) s = -INFINITY;
                    }
                    pv[cb][r] = s;
                    tmax[r] = fmaxf(tmax[r], s);
                }
            }
            #pragma unroll
            for (int r = 0; r < 4; r++) {
                #pragma unroll
                for (int off = 1; off < 16; off <<= 1)
                    tmax[r] = fmaxf(tmax[r], __shfl_xor(tmax[r], off, 64));
            }
            float scl[4], rsum[4];
            #pragma unroll
            for (int r = 0; r < 4; r++) {
                float mn = fmaxf(mrow[r], tmax[r]);
                scl[r] = __expf(mrow[r] - mn);   // first tile: exp(-inf)=0
                mrow[r] = mn;
                rsum[r] = 0.f;
            }
            #pragma unroll
            for (int cb = 0; cb < 4; cb++) {
                #pragma unroll
                for (int r = 0; r < 4; r++) {
                    float e = __expf(pv[cb][r] - mrow[r]);
                    pv[cb][r] = e;
                    rsum[r] += e;
                }
            }
            #pragma unroll
            for (int r = 0; r < 4; r++) {
                #pragma unroll
                for (int off = 1; off < 16; off <<= 1)
                    rsum[r] += __shfl_xor(rsum[r], off, 64);
                ell[r] = ell[r] * scl[r] + rsum[r];
            }
            #pragma unroll
            for (int sb = 0; sb < 4; sb++)
                #pragma unroll
                for (int r = 0; r < 4; r++) acc[sb][r] *= scl[r];

            // P -> per-wave LDS (re-fragment for PV A operand)
            #pragma unroll
            for (int cb = 0; cb < 4; cb++)
                #pragma unroll
                for (int r = 0; r < 4; r++)
                    Ps[w][lg * 4 + r][cb * 16 + l15] = f2bf(pv[cb][r]);
            asm volatile("s_waitcnt lgkmcnt(0)" ::: "memory");   // own-wave writes visible

            // y += P V   (A = P from Ps, B[k][n] = V[kv][sb*16+n] from Vs = V^T)
            #pragma unroll
            for (int kk = 0; kk < 2; kk++) {
                bf16x8 afr = *reinterpret_cast<const bf16x8*>(&Ps[w][l15][kk * 32 + lg * 8]);
                #pragma unroll
                for (int sb = 0; sb < 4; sb++) {
                    bf16x8 bfr = *reinterpret_cast<const bf16x8*>(&Vs[sb * 16 + l15][kk * 32 + lg * 8]);
                    acc[sb] = __builtin_amdgcn_mfma_f32_16x16x32_bf16(afr, bfr, acc[sb], 0, 0, 0);
                }
            }
            __syncthreads();
        }

        // epilogue: y / ell -> y_bf [m][h*64+s]
        #pragma unroll
        for (int sb = 0; sb < 4; sb++) {
            #pragma unroll
            for (int r = 0; r < 4; r++) {
                int q = qi * 64 + w * 16 + lg * 4 + r;
                float v = acc[sb][r] / ell[r];
                y_bf[((size_t)(b * T + q)) * 1024 + h * 64 + sb * 16 + l15] = f2bf(v);
            }
        }
    }
}

// ---------- launch ----------
extern "C" void kernel_launch(void* const* d_in, const int* in_sizes, int n_in,
                              void* d_out, int out_size, void* d_ws, size_t ws_size,
                              hipStream_t stream) {
    const float* x  = (const float*)d_in[0];
    const float* Wq = (const float*)d_in[1];
    const float* Wk = (const float*)d_in[2];
    const float* Wv = (const float*)d_in[3];
    const float* Wp = (const float*)d_in[4];
    const float* bp = (const float*)d_in[5];
    float* out = (float*)d_out;

    char* ws = (char*)d_ws;
    // layout (bytes): requires ws_size >= 48 MB
    unsigned short* x_bf  = (unsigned short*)(ws);                           // 8 MB
    unsigned short* Wt    = (unsigned short*)(ws + ((size_t)8  << 20));      // 6 MB
    unsigned short* Wp_bf = (unsigned short*)(ws + ((size_t)14 << 20));      // 2 MB
    unsigned short* q_nat = (unsigned short*)(ws + ((size_t)16 << 20));      // 8 MB
    unsigned short* k_nat = (unsigned short*)(ws + ((size_t)24 << 20));      // 8 MB
    unsigned short* vT    = (unsigned short*)(ws + ((size_t)32 << 20));      // 8 MB
    unsigned short* y_bf  = (unsigned short*)(ws + ((size_t)40 << 20));      // 8 MB

    k_cvt<<<4096, 256, 0, stream>>>(x, x_bf, 4194304 / 4);
    k_cvt<<<1024, 256, 0, stream>>>(Wp, Wp_bf, 1048576 / 4);
    k_cvt_wt<<<768, 256, 0, stream>>>(Wq, Wk, Wv, Wt);
    k_gemm<0><<<24 * 32, 256, 0, stream>>>(x_bf, Wt, 4096, 3072, 1024,
                                           q_nat, k_nat, vT, nullptr, nullptr);
    k_attn<<<512, 256, 0, stream>>>(q_nat, k_nat, vT, y_bf);
    k_gemm<1><<<8 * 32, 256, 0, stream>>>(y_bf, Wp_bf, 4096, 1024, 1024,
                                          nullptr, nullptr, nullptr, out, bp);
}

// Round 2
// 153.070 us; speedup vs baseline: 1.0585x; 1.0585x over previous
//
#include <hip/hip_runtime.h>
#include <hip/hip_bf16.h>
#include <cmath>

// ---------- types ----------
typedef __attribute__((ext_vector_type(8))) short bf16x8;   // 8 bf16 in 4 VGPRs (MFMA A/B frag)
typedef __attribute__((ext_vector_type(4))) float f32x4;    // MFMA C/D frag

__device__ __forceinline__ unsigned short f2bf(float f) {
    union { float f; unsigned int i; } c; c.f = f;
    unsigned int i = c.i;
    unsigned int r = i + 0x7FFF + ((i >> 16) & 1);   // round-to-nearest-even
    return (unsigned short)(r >> 16);
}

// async global->LDS, 16B per lane. LDS dest must be wave-uniform base (+lane*16 implicit).
__device__ __forceinline__ void gload_lds16(const unsigned short* g, unsigned short* l) {
    __builtin_amdgcn_global_load_lds((const __attribute__((address_space(1))) unsigned int*)g,
                                     (__attribute__((address_space(3))) unsigned int*)l, 16, 0, 0);
}

// ---------- conversion kernels ----------
__global__ void k_cvt(const float* __restrict__ src, unsigned short* __restrict__ dst, int n4) {
    int i = blockIdx.x * blockDim.x + threadIdx.x;
    if (i < n4) {
        float4 v = reinterpret_cast<const float4*>(src)[i];
        ushort4 o;
        o.x = f2bf(v.x); o.y = f2bf(v.y); o.z = f2bf(v.z); o.w = f2bf(v.w);
        reinterpret_cast<ushort4*>(dst)[i] = o;
    }
}

// Wq/Wk/Wv [H=16][C=1024][S=64] f32  ->  Wt [n=sec*1024+h*64+s][c] bf16 (K-contiguous)
__global__ void k_cvt_wt(const float* __restrict__ Wq, const float* __restrict__ Wk,
                         const float* __restrict__ Wv, unsigned short* __restrict__ Wt) {
    __shared__ unsigned short lt[64][72];   // [s][c], padded
    int bid = blockIdx.x;
    int ct  = bid & 15;
    int h   = (bid >> 4) & 15;
    int sec = bid >> 8;
    const float* W = (sec == 0) ? Wq : ((sec == 1) ? Wk : Wv);
    int t = threadIdx.x;
    #pragma unroll
    for (int q = 0; q < 4; q++) {
        int id = t + q * 256;          // 0..1023
        int c  = id >> 4;              // 0..63
        int s4 = (id & 15) * 4;        // 0..60
        float4 v = *reinterpret_cast<const float4*>(&W[((size_t)(h * 1024) + (ct * 64 + c)) * 64 + s4]);
        lt[s4 + 0][c] = f2bf(v.x);
        lt[s4 + 1][c] = f2bf(v.y);
        lt[s4 + 2][c] = f2bf(v.z);
        lt[s4 + 3][c] = f2bf(v.w);
    }
    __syncthreads();
    #pragma unroll
    for (int q = 0; q < 2; q++) {
        int id = t + q * 256;          // 0..511
        int s  = id >> 3;              // 0..63
        int c8 = (id & 7) * 8;         // 0..56
        bf16x8 val = *reinterpret_cast<const bf16x8*>(&lt[s][c8]);
        int n = sec * 1024 + h * 64 + s;
        *reinterpret_cast<bf16x8*>(&Wt[(size_t)n * 1024 + ct * 64 + c8]) = val;
    }
}

// ---------- GEMM (m97 structure): C[M][N] = A[M][K] * Bt[N][K]^T ----------
// LDS linear [128][32] (global_load_lds width=16), 128x128 tile, 4 waves, 4x4 acc.
// MODE 0: QKV -> q_nat [m][win], k_nat [m][win], vT [b][h][s][t]
// MODE 1: proj -> out f32 [m][n] + bias
template <int MODE>
__launch_bounds__(256)
__global__ void k_gemm(const unsigned short* __restrict__ A,
                       const unsigned short* __restrict__ Bt,
                       int M, int N, int K,
                       unsigned short* __restrict__ q_nat,
                       unsigned short* __restrict__ k_nat,
                       unsigned short* __restrict__ vT,
                       float* __restrict__ out, const float* __restrict__ bp) {
    __shared__ unsigned short Asm[128][32];   // linear: row stride 64B (global_load_lds order)
    __shared__ unsigned short Bsm[128][32];
    const int nb = N >> 7;
    int bid = blockIdx.x;
    int n0 = (bid % nb) << 7;
    int m0 = (bid / nb) << 7;
    int t = threadIdx.x;
    int lane = t & 63, w = t >> 6;
    int wr = w >> 1, wc = w & 1;
    int l15 = lane & 15, lg = lane >> 4;
    int lr = lane >> 2;          // 0..15 row within 16-row chunk
    int lc = (lane & 3) << 3;    // 0,8,16,24 col (elements)

    f32x4 acc[4][4];
    #pragma unroll
    for (int i = 0; i < 4; i++)
        #pragma unroll
        for (int j = 0; j < 4; j++) acc[i][j] = (f32x4){0.f, 0.f, 0.f, 0.f};

    for (int kt = 0; kt < K; kt += 32) {
        #pragma unroll
        for (int q = 0; q < 2; q++) {
            int r0 = w * 32 + q * 16;   // wave-uniform row base
            gload_lds16(&A[(size_t)(m0 + r0 + lr) * K + kt + lc], &Asm[r0][0]);
            gload_lds16(&Bt[(size_t)(n0 + r0 + lr) * K + kt + lc], &Bsm[r0][0]);
        }
        __syncthreads();
        bf16x8 af[4], bfrag[4];
        #pragma unroll
        for (int mi = 0; mi < 4; mi++)
            af[mi] = *reinterpret_cast<const bf16x8*>(&Asm[wr * 64 + mi * 16 + l15][lg * 8]);
        #pragma unroll
        for (int nj = 0; nj < 4; nj++)
            bfrag[nj] = *reinterpret_cast<const bf16x8*>(&Bsm[wc * 64 + nj * 16 + l15][lg * 8]);
        #pragma unroll
        for (int mi = 0; mi < 4; mi++)
            #pragma unroll
            for (int nj = 0; nj < 4; nj++)
                acc[mi][nj] = __builtin_amdgcn_mfma_f32_16x16x32_bf16(af[mi], bfrag[nj], acc[mi][nj], 0, 0, 0);
        __syncthreads();
    }

    #pragma unroll
    for (int mi = 0; mi < 4; mi++) {
        #pragma unroll
        for (int nj = 0; nj < 4; nj++) {
            #pragma unroll
            for (int r = 0; r < 4; r++) {
                int m = m0 + wr * 64 + mi * 16 + lg * 4 + r;
                int n = n0 + wc * 64 + nj * 16 + l15;
                float v = acc[mi][nj][r];
                if (MODE == 0) {
                    int sec = n >> 10;
                    int win = n & 1023;
                    if (sec == 0) {
                        q_nat[(size_t)m * 1024 + win] = f2bf(v);
                    } else if (sec == 1) {
                        k_nat[(size_t)m * 1024 + win] = f2bf(v);
                    } else {
                        int b = m >> 11, tt = m & 2047;
                        int h = win >> 6, s = win & 63;
                        vT[(((size_t)(b * 16 + h)) * 64 + s) * 2048 + tt] = f2bf(v);
                    }
                } else {
                    out[(size_t)m * 1024 + n] = v + bp[n];
                }
            }
        }
    }
}

// ---------- flash attention ----------
// grid = 1024 blocks: bid = qidx*32 + (b*16+h), qi = 31-qidx (longest blocks first).
// 4 waves; wave owns 16 q-rows of its 64-row q-tile. T14: prefetch next K/V tile to
// regs before compute, write to LDS after the read-barrier.
__launch_bounds__(256, 4)
__global__ void k_attn(const unsigned short* __restrict__ q_nat,
                       const unsigned short* __restrict__ k_nat,
                       const unsigned short* __restrict__ vT,
                       unsigned short* __restrict__ y_bf) {
    __shared__ unsigned short Ks[64][72];       // K tile [kv][s], padded (2-way-free)
    __shared__ unsigned short Vs[64][72];       // V^T tile [s][kv], padded
    __shared__ unsigned short Ps[4][16][80];    // per-wave P tile [q][kv]; 160B rows: write-conflict-free
    const int T = 2048, H = 16;
    int bid = blockIdx.x;
    int bh = bid & 31;
    int qi = 31 - (bid >> 5);
    int h = bh & 15, b = bh >> 4;
    int t = threadIdx.x;
    int lane = t & 63, w = t >> 6;
    int l15 = lane & 15, lg = lane >> 4;

    // staging geometry: thread t, chunk q: id = t + q*256; row = id>>3 (0..63), col8 = (id&7)*8
    int sr[2], sc[2];
    #pragma unroll
    for (int q = 0; q < 2; q++) { int id = t + q * 256; sr[q] = id >> 3; sc[q] = (id & 7) << 3; }
    const unsigned short* kbase = &k_nat[((size_t)(b * T)) * 1024 + h * 64];
    const unsigned short* vbase = &vT[(((size_t)(b * H + h)) * 64) * 2048];

    // Q fragments: wave w owns q-rows qi*64 + w*16 .. +16
    bf16x8 qf[2];
    {
        int qrow = qi * 64 + w * 16 + l15;
        #pragma unroll
        for (int kk = 0; kk < 2; kk++)
            qf[kk] = *reinterpret_cast<const bf16x8*>(
                &q_nat[((size_t)(b * T + qrow)) * 1024 + h * 64 + kk * 32 + lg * 8]);
    }

    float mrow[4], ell[4];
    f32x4 acc[4];
    #pragma unroll
    for (int r = 0; r < 4; r++) { mrow[r] = -INFINITY; ell[r] = 0.f; }
    #pragma unroll
    for (int sb = 0; sb < 4; sb++) acc[sb] = (f32x4){0.f, 0.f, 0.f, 0.f};

    // prologue: stage tile 0
    bf16x8 kreg[2], vreg[2];
    #pragma unroll
    for (int q = 0; q < 2; q++) {
        kreg[q] = *reinterpret_cast<const bf16x8*>(&kbase[(size_t)(0 * 64 + sr[q]) * 1024 + sc[q]]);
        vreg[q] = *reinterpret_cast<const bf16x8*>(&vbase[(size_t)sr[q] * 2048 + 0 * 64 + sc[q]]);
    }
    #pragma unroll
    for (int q = 0; q < 2; q++) {
        *reinterpret_cast<bf16x8*>(&Ks[sr[q]][sc[q]]) = kreg[q];
        *reinterpret_cast<bf16x8*>(&Vs[sr[q]][sc[q]]) = vreg[q];
    }
    __syncthreads();

    for (int j = 0; j <= qi; j++) {
        bool pre = (j < qi);
        if (pre) {   // issue next-tile loads early; latency hides under compute below
            #pragma unroll
            for (int q = 0; q < 2; q++) {
                kreg[q] = *reinterpret_cast<const bf16x8*>(&kbase[(size_t)((j + 1) * 64 + sr[q]) * 1024 + sc[q]]);
                vreg[q] = *reinterpret_cast<const bf16x8*>(&vbase[(size_t)sr[q] * 2048 + (j + 1) * 64 + sc[q]]);
            }
        }

        // S = Q K^T
        f32x4 sacc[4];
        #pragma unroll
        for (int cb = 0; cb < 4; cb++) {
            sacc[cb] = (f32x4){0.f, 0.f, 0.f, 0.f};
            #pragma unroll
            for (int kk = 0; kk < 2; kk++) {
                bf16x8 bfr = *reinterpret_cast<const bf16x8*>(&Ks[cb * 16 + l15][kk * 32 + lg * 8]);
                sacc[cb] = __builtin_amdgcn_mfma_f32_16x16x32_bf16(qf[kk], bfr, sacc[cb], 0, 0, 0);
            }
        }

        // online softmax
        float pv[4][4];
        float tmax[4];
        bool diag = (j == qi);
        #pragma unroll
        for (int r = 0; r < 4; r++) tmax[r] = -INFINITY;
        #pragma unroll
        for (int cb = 0; cb < 4; cb++) {
            #pragma unroll
            for (int r = 0; r < 4; r++) {
                float s = sacc[cb][r] * 0.125f;
                if (diag) {
                    int kv = cb * 16 + l15;
                    int qq = w * 16 + lg * 4 + r;
                    if (kv > qq) s = -INFINITY;
                }
                pv[cb][r] = s;
                tmax[r] = fmaxf(tmax[r], s);
            }
        }
        #pragma unroll
        for (int r = 0; r < 4; r++) {
            #pragma unroll
            for (int off = 1; off < 16; off <<= 1)
                tmax[r] = fmaxf(tmax[r], __shfl_xor(tmax[r], off, 64));
        }
        float scl[4], rsum[4];
        #pragma unroll
        for (int r = 0; r < 4; r++) {
            float mn = fmaxf(mrow[r], tmax[r]);
            scl[r] = __expf(mrow[r] - mn);
            mrow[r] = mn;
            rsum[r] = 0.f;
        }
        #pragma unroll
        for (int cb = 0; cb < 4; cb++) {
            #pragma unroll
            for (int r = 0; r < 4; r++) {
                float e = __expf(pv[cb][r] - mrow[r]);
                pv[cb][r] = e;
                rsum[r] += e;
            }
        }
        #pragma unroll
        for (int r = 0; r < 4; r++) {
            #pragma unroll
            for (int off = 1; off < 16; off <<= 1)
                rsum[r] += __shfl_xor(rsum[r], off, 64);
            ell[r] = ell[r] * scl[r] + rsum[r];
        }
        #pragma unroll
        for (int sb = 0; sb < 4; sb++)
            #pragma unroll
            for (int r = 0; r < 4; r++) acc[sb][r] *= scl[r];

        // P -> per-wave LDS (re-fragment for PV A operand)
        #pragma unroll
        for (int cb = 0; cb < 4; cb++)
            #pragma unroll
            for (int r = 0; r < 4; r++)
                Ps[w][lg * 4 + r][cb * 16 + l15] = f2bf(pv[cb][r]);
        asm volatile("s_waitcnt lgkmcnt(0)" ::: "memory");   // own-wave writes visible

        // y += P V
        #pragma unroll
        for (int kk = 0; kk < 2; kk++) {
            bf16x8 afr = *reinterpret_cast<const bf16x8*>(&Ps[w][l15][kk * 32 + lg * 8]);
            #pragma unroll
            for (int sb = 0; sb < 4; sb++) {
                bf16x8 bfr = *reinterpret_cast<const bf16x8*>(&Vs[sb * 16 + l15][kk * 32 + lg * 8]);
                acc[sb] = __builtin_amdgcn_mfma_f32_16x16x32_bf16(afr, bfr, acc[sb], 0, 0, 0);
            }
        }
        __syncthreads();            // all waves done reading Ks/Vs of tile j

        if (pre) {                  // write prefetched tile j+1 (vmcnt wait lands here)
            #pragma unroll
            for (int q = 0; q < 2; q++) {
                *reinterpret_cast<bf16x8*>(&Ks[sr[q]][sc[q]]) = kreg[q];
                *reinterpret_cast<bf16x8*>(&Vs[sr[q]][sc[q]]) = vreg[q];
            }
        }
        __syncthreads();            // tile j+1 visible to all
    }

    // epilogue: y / ell -> y_bf [m][h*64+s]
    #pragma unroll
    for (int sb = 0; sb < 4; sb++) {
        #pragma unroll
        for (int r = 0; r < 4; r++) {
            int q = qi * 64 + w * 16 + lg * 4 + r;
            float v = acc[sb][r] / ell[r];
            y_bf[((size_t)(b * T + q)) * 1024 + h * 64 + sb * 16 + l15] = f2bf(v);
        }
    }
}

// ---------- launch ----------
extern "C" void kernel_launch(void* const* d_in, const int* in_sizes, int n_in,
                              void* d_out, int out_size, void* d_ws, size_t ws_size,
                              hipStream_t stream) {
    const float* x  = (const float*)d_in[0];
    const float* Wq = (const float*)d_in[1];
    const float* Wk = (const float*)d_in[2];
    const float* Wv = (const float*)d_in[3];
    const float* Wp = (const float*)d_in[4];
    const float* bp = (const float*)d_in[5];
    float* out = (float*)d_out;

    char* ws = (char*)d_ws;
    unsigned short* x_bf  = (unsigned short*)(ws);                           // 8 MB
    unsigned short* Wt    = (unsigned short*)(ws + ((size_t)8  << 20));      // 6 MB
    unsigned short* Wp_bf = (unsigned short*)(ws + ((size_t)14 << 20));      // 2 MB
    unsigned short* q_nat = (unsigned short*)(ws + ((size_t)16 << 20));      // 8 MB
    unsigned short* k_nat = (unsigned short*)(ws + ((size_t)24 << 20));      // 8 MB
    unsigned short* vT    = (unsigned short*)(ws + ((size_t)32 << 20));      // 8 MB
    unsigned short* y_bf  = (unsigned short*)(ws + ((size_t)40 << 20));      // 8 MB

    k_cvt<<<4096, 256, 0, stream>>>(x, x_bf, 4194304 / 4);
    k_cvt<<<1024, 256, 0, stream>>>(Wp, Wp_bf, 1048576 / 4);
    k_cvt_wt<<<768, 256, 0, stream>>>(Wq, Wk, Wv, Wt);
    k_gemm<0><<<24 * 32, 256, 0, stream>>>(x_bf, Wt, 4096, 3072, 1024,
                                           q_nat, k_nat, vT, nullptr, nullptr);
    k_attn<<<1024, 256, 0, stream>>>(q_nat, k_nat, vT, y_bf);
    k_gemm<1><<<8 * 32, 256, 0, stream>>>(y_bf, Wp_bf, 4096, 1024, 1024,
                                          nullptr, nullptr, nullptr, out, bp);
}

// Round 3
// 140.844 us; speedup vs baseline: 1.1503x; 1.0868x over previous
//
#include <hip/hip_runtime.h>
#include <hip/hip_bf16.h>
#include <cmath>

// ---------- types ----------
typedef __attribute__((ext_vector_type(8))) short bf16x8;    // 8 bf16 (4 VGPRs) MFMA A/B frag
typedef __attribute__((ext_vector_type(4))) float f32x4;     // 16x16 C/D frag
typedef __attribute__((ext_vector_type(16))) float f32x16;   // 32x32 C/D frag

__device__ __forceinline__ unsigned short f2bf(float f) {
    union { float f; unsigned int i; } c; c.f = f;
    unsigned int i = c.i;
    unsigned int r = i + 0x7FFF + ((i >> 16) & 1);   // RTNE
    return (unsigned short)(r >> 16);
}

// async global->LDS, 16B/lane. LDS dest: wave-uniform base (+lane*16 implicit); global src per-lane.
__device__ __forceinline__ void gload_lds16(const unsigned short* g, unsigned short* l) {
    __builtin_amdgcn_global_load_lds((const __attribute__((address_space(1))) unsigned int*)g,
                                     (__attribute__((address_space(3))) unsigned int*)l, 16, 0, 0);
}

__device__ __forceinline__ float bperm_f(int srclane, float v) {
    return __int_as_float(__builtin_amdgcn_ds_bpermute(srclane << 2, __float_as_int(v)));
}

// ---------- conversion kernels ----------
__global__ void k_cvt(const float* __restrict__ src, unsigned short* __restrict__ dst, int n4) {
    int i = blockIdx.x * blockDim.x + threadIdx.x;
    if (i < n4) {
        float4 v = reinterpret_cast<const float4*>(src)[i];
        ushort4 o;
        o.x = f2bf(v.x); o.y = f2bf(v.y); o.z = f2bf(v.z); o.w = f2bf(v.w);
        reinterpret_cast<ushort4*>(dst)[i] = o;
    }
}

// Wq/Wk/Wv [H=16][C=1024][S=64] f32 -> Wt [n=sec*1024+h*64+s][c] bf16 (K-contiguous)
__global__ void k_cvt_wt(const float* __restrict__ Wq, const float* __restrict__ Wk,
                         const float* __restrict__ Wv, unsigned short* __restrict__ Wt) {
    __shared__ unsigned short lt[64][72];
    int bid = blockIdx.x;
    int ct  = bid & 15;
    int h   = (bid >> 4) & 15;
    int sec = bid >> 8;
    const float* W = (sec == 0) ? Wq : ((sec == 1) ? Wk : Wv);
    int t = threadIdx.x;
    #pragma unroll
    for (int q = 0; q < 4; q++) {
        int id = t + q * 256;
        int c  = id >> 4;
        int s4 = (id & 15) * 4;
        float4 v = *reinterpret_cast<const float4*>(&W[((size_t)(h * 1024) + (ct * 64 + c)) * 64 + s4]);
        lt[s4 + 0][c] = f2bf(v.x);
        lt[s4 + 1][c] = f2bf(v.y);
        lt[s4 + 2][c] = f2bf(v.z);
        lt[s4 + 3][c] = f2bf(v.w);
    }
    __syncthreads();
    #pragma unroll
    for (int q = 0; q < 2; q++) {
        int id = t + q * 256;
        int s  = id >> 3;
        int c8 = (id & 7) * 8;
        bf16x8 val = *reinterpret_cast<const bf16x8*>(&lt[s][c8]);
        int n = sec * 1024 + h * 64 + s;
        *reinterpret_cast<bf16x8*>(&Wt[(size_t)n * 1024 + ct * 64 + c8]) = val;
    }
}

// ---------- GEMM (m97 structure): C[M][N] = A[M][K] * Bt[N][K]^T ----------
// MODE 0: QKV -> q_nat (pre-scaled by 0.125), k_nat, vT [b][h][s][t]
// MODE 1: proj -> out f32 + bias
template <int MODE>
__launch_bounds__(256)
__global__ void k_gemm(const unsigned short* __restrict__ A,
                       const unsigned short* __restrict__ Bt,
                       int M, int N, int K,
                       unsigned short* __restrict__ q_nat,
                       unsigned short* __restrict__ k_nat,
                       unsigned short* __restrict__ vT,
                       float* __restrict__ out, const float* __restrict__ bp) {
    __shared__ unsigned short Asm[128][32];
    __shared__ unsigned short Bsm[128][32];
    const int nb = N >> 7;
    int bid = blockIdx.x;
    int n0 = (bid % nb) << 7;
    int m0 = (bid / nb) << 7;
    int t = threadIdx.x;
    int lane = t & 63, w = t >> 6;
    int wr = w >> 1, wc = w & 1;
    int l15 = lane & 15, lg = lane >> 4;
    int lr = lane >> 2;
    int lc = (lane & 3) << 3;

    f32x4 acc[4][4];
    #pragma unroll
    for (int i = 0; i < 4; i++)
        #pragma unroll
        for (int j = 0; j < 4; j++) acc[i][j] = (f32x4){0.f, 0.f, 0.f, 0.f};

    for (int kt = 0; kt < K; kt += 32) {
        #pragma unroll
        for (int q = 0; q < 2; q++) {
            int r0 = w * 32 + q * 16;
            gload_lds16(&A[(size_t)(m0 + r0 + lr) * K + kt + lc], &Asm[r0][0]);
            gload_lds16(&Bt[(size_t)(n0 + r0 + lr) * K + kt + lc], &Bsm[r0][0]);
        }
        __syncthreads();
        bf16x8 af[4], bfrag[4];
        #pragma unroll
        for (int mi = 0; mi < 4; mi++)
            af[mi] = *reinterpret_cast<const bf16x8*>(&Asm[wr * 64 + mi * 16 + l15][lg * 8]);
        #pragma unroll
        for (int nj = 0; nj < 4; nj++)
            bfrag[nj] = *reinterpret_cast<const bf16x8*>(&Bsm[wc * 64 + nj * 16 + l15][lg * 8]);
        #pragma unroll
        for (int mi = 0; mi < 4; mi++)
            #pragma unroll
            for (int nj = 0; nj < 4; nj++)
                acc[mi][nj] = __builtin_amdgcn_mfma_f32_16x16x32_bf16(af[mi], bfrag[nj], acc[mi][nj], 0, 0, 0);
        __syncthreads();
    }

    #pragma unroll
    for (int mi = 0; mi < 4; mi++) {
        #pragma unroll
        for (int nj = 0; nj < 4; nj++) {
            #pragma unroll
            for (int r = 0; r < 4; r++) {
                int m = m0 + wr * 64 + mi * 16 + lg * 4 + r;
                int n = n0 + wc * 64 + nj * 16 + l15;
                float v = acc[mi][nj][r];
                if (MODE == 0) {
                    int sec = n >> 10;
                    int win = n & 1023;
                    if (sec == 0) {
                        q_nat[(size_t)m * 1024 + win] = f2bf(v * 0.125f);   // fold 1/sqrt(S); 2^-3 exact
                    } else if (sec == 1) {
                        k_nat[(size_t)m * 1024 + win] = f2bf(v);
                    } else {
                        int b = m >> 11, tt = m & 2047;
                        int h = win >> 6, s = win & 63;
                        vT[(((size_t)(b * 16 + h)) * 64 + s) * 2048 + tt] = f2bf(v);
                    }
                } else {
                    out[(size_t)m * 1024 + n] = v + bp[n];
                }
            }
        }
    }
}

// ---------- flash attention (m214-style: 32x32 swapped QK^T, in-register softmax) ----------
// 512 blocks: bid = qidx*32 + bh, p = 15-qidx (longest first). 4 warps, warp owns 32 q-rows
// of the 128-row q-tile. KVBLK=64, K/V double-buffered LDS with XOR-swizzle (T2, rule #21).
__launch_bounds__(256, 2)
__global__ void k_attn(const unsigned short* __restrict__ q_nat,
                       const unsigned short* __restrict__ k_nat,
                       const unsigned short* __restrict__ vT,
                       unsigned short* __restrict__ y_bf) {
    __shared__ __align__(16) unsigned short Ks[2][64][64];   // [buf][kv][d], rows XOR-swizzled
    __shared__ __align__(16) unsigned short Vs[2][64][64];   // [buf][d][kv], rows XOR-swizzled
    const int T = 2048, H = 16;
    int bid = blockIdx.x;
    int bh = bid & 31;
    int p = 15 - (bid >> 5);
    int h = bh & 15, b = bh >> 4;
    int q0 = p << 7;
    int t = threadIdx.x;
    int lane = t & 63, w = t >> 6;
    int l31 = lane & 31, hi = lane >> 5;
    int warp_q0 = q0 + w * 32;
    int qg = warp_q0 + l31;          // this lane's q-row (S^T col)
    int jmax = 2 * p + 1;

    const unsigned short* kbase = k_nat + (size_t)(b * T) * 1024 + h * 64;
    const unsigned short* vbase = vT + ((size_t)(b * H + h) * 64) * 2048;

    // staging: thread t, part r: LDS row = r*32 + (t>>3), col byte = (t&7)*16 (linear dest);
    // source col pre-swizzled so READ col ^ ((row&7)<<4) sees natural data.
    int srow = t >> 3;                               // 0..31
    int scol = ((t & 7) ^ (srow & 7)) << 3;          // elems
    int wrow8 = (t >> 6) << 3;                       // wave-uniform part of srow

    auto STAGE = [&](int j, int buf) {
        #pragma unroll
        for (int r = 0; r < 2; r++) {
            int grow = r * 32 + srow;
            gload_lds16(kbase + (size_t)(j * 64 + grow) * 1024 + scol, &Ks[buf][r * 32 + wrow8][0]);
            gload_lds16(vbase + (size_t)grow * 2048 + j * 64 + scol, &Vs[buf][r * 32 + wrow8][0]);
        }
    };

    // Q fragments (B operand): lane holds Q[q=qg][k = tt*16 + hi*8 + 0..7], pre-scaled by 0.125
    bf16x8 qf[4];
    #pragma unroll
    for (int tt = 0; tt < 4; tt++)
        qf[tt] = *reinterpret_cast<const bf16x8*>(
            q_nat + (size_t)(b * T + qg) * 1024 + h * 64 + tt * 16 + hi * 8);

    f32x16 acc0, acc1;               // O cols s = l31 (nb=0), 32+l31 (nb=1); rows q via reg pattern
    #pragma unroll
    for (int r = 0; r < 16; r++) { acc0[r] = 0.f; acc1[r] = 0.f; }
    float m = -INFINITY, ell = 0.f;

    STAGE(0, 0);
    __syncthreads();
    int cur = 0;

    for (int j = 0; j <= jmax; j++) {
        if (j < jmax) STAGE(j + 1, cur ^ 1);         // T14: issue early, drain at barrier

        bool active = (j * 64 <= warp_q0 + 31);
        if (active) {
            const char* kb = (const char*)&Ks[cur][0][0];
            const char* vb = (const char*)&Vs[cur][0][0];
            int rsw = (l31 & 7) << 4;                // read-side XOR (row&7 == l31&7 for both halves)

            // S^T = K · Q^T : lane holds col q=qg, rows kv = kvb(r) + 4*hi (+32 for s1)
            f32x16 s0, s1;
            #pragma unroll
            for (int r = 0; r < 16; r++) { s0[r] = 0.f; s1[r] = 0.f; }
            #pragma unroll
            for (int tt = 0; tt < 4; tt++) {
                int cb = (tt * 32 + hi * 16) ^ rsw;
                bf16x8 kf0 = *reinterpret_cast<const bf16x8*>(kb + l31 * 128 + cb);
                bf16x8 kf1 = *reinterpret_cast<const bf16x8*>(kb + (32 + l31) * 128 + cb);
                s0 = __builtin_amdgcn_mfma_f32_32x32x16_bf16(kf0, qf[tt], s0, 0, 0, 0);
                s1 = __builtin_amdgcn_mfma_f32_32x32x16_bf16(kf1, qf[tt], s1, 0, 0, 0);
            }

            // causal mask (diagonal tiles only)
            bool need_mask = (j * 64 + 63 > warp_q0);
            if (need_mask) {
                #pragma unroll
                for (int r = 0; r < 16; r++) {
                    int kvr = (r & 3) + 8 * (r >> 2) + 4 * hi + j * 64;
                    if (kvr > qg) s0[r] = -INFINITY;
                    if (kvr + 32 > qg) s1[r] = -INFINITY;
                }
            }

            // row max (in-lane + pair exchange with lane^32)
            float tmax = -INFINITY;
            #pragma unroll
            for (int r = 0; r < 16; r++) tmax = fmaxf(tmax, fmaxf(s0[r], s1[r]));
            tmax = fmaxf(tmax, __shfl_xor(tmax, 32, 64));

            // defer-max (T13): rescale only when tile max grew past THR=8
            if (!__all(tmax <= m + 8.0f)) {
                float mn = fmaxf(m, tmax);
                float scl = __expf(m - mn);
                m = mn; ell *= scl;
                #pragma unroll
                for (int r = 0; r < 16; r++) {
                    float sv = bperm_f((r & 3) + 8 * (r >> 2) + 4 * hi, scl);
                    acc0[r] *= sv; acc1[r] *= sv;
                }
            }

            // P = exp(S - m), row sum
            float rs = 0.f;
            #pragma unroll
            for (int r = 0; r < 16; r++) {
                s0[r] = __expf(s0[r] - m); rs += s0[r];
                s1[r] = __expf(s1[r] - m); rs += s1[r];
            }
            rs += __shfl_xor(rs, 32, 64);
            ell += rs;

            // pack P to bf16 pairs: c[i] = (P[kv=2i-ish], ...) per cvt_pk
            unsigned int c[16];
            #pragma unroll
            for (int i = 0; i < 8; i++) {
                asm("v_cvt_pk_bf16_f32 %0, %1, %2" : "=v"(c[i]) : "v"(s0[2 * i]), "v"(s0[2 * i + 1]));
                asm("v_cvt_pk_bf16_f32 %0, %1, %2" : "=v"(c[8 + i]) : "v"(s1[2 * i]), "v"(s1[2 * i + 1]));
            }
            // assemble PV A-frags: word pairs from (clo,chi) with lane^32 exchange
            bf16x8 pa[4];
            #pragma unroll
            for (int ks = 0; ks < 4; ks++) {
                unsigned int clo0 = c[ks * 4 + 0], clo1 = c[ks * 4 + 1];
                unsigned int chi0 = c[ks * 4 + 2], chi1 = c[ks * 4 + 3];
                unsigned int pl0 = (unsigned int)__shfl_xor((int)clo0, 32, 64);
                unsigned int pl1 = (unsigned int)__shfl_xor((int)clo1, 32, 64);
                unsigned int ph0 = (unsigned int)__shfl_xor((int)chi0, 32, 64);
                unsigned int ph1 = (unsigned int)__shfl_xor((int)chi1, 32, 64);
                union { unsigned int u[4]; bf16x8 v; } fr;
                fr.u[0] = hi ? ph0 : clo0;
                fr.u[1] = hi ? ph1 : clo1;
                fr.u[2] = hi ? chi0 : pl0;
                fr.u[3] = hi ? chi1 : pl1;
                pa[ks] = fr.v;
            }

            // O += P · V
            #pragma unroll
            for (int ks = 0; ks < 4; ks++) {
                int cb = (ks * 32 + hi * 16) ^ rsw;
                bf16x8 v0 = *reinterpret_cast<const bf16x8*>(vb + l31 * 128 + cb);
                bf16x8 v1 = *reinterpret_cast<const bf16x8*>(vb + (32 + l31) * 128 + cb);
                acc0 = __builtin_amdgcn_mfma_f32_32x32x16_bf16(pa[ks], v0, acc0, 0, 0, 0);
                acc1 = __builtin_amdgcn_mfma_f32_32x32x16_bf16(pa[ks], v1, acc1, 0, 0, 0);
            }
        }
        __syncthreads();             // drains staged loads (compiler waitcnt) + tile handoff
        cur ^= 1;
    }

    // epilogue: O / ell
    float rinv = 1.0f / ell;
    #pragma unroll
    for (int r = 0; r < 16; r++) {
        int qr = (r & 3) + 8 * (r >> 2) + 4 * hi;
        float rv = bperm_f(qr, rinv);
        size_t row = (size_t)(b * T + warp_q0 + qr) * 1024 + h * 64;
        y_bf[row + l31] = f2bf(acc0[r] * rv);
        y_bf[row + 32 + l31] = f2bf(acc1[r] * rv);
    }
}

// ---------- launch ----------
extern "C" void kernel_launch(void* const* d_in, const int* in_sizes, int n_in,
                              void* d_out, int out_size, void* d_ws, size_t ws_size,
                              hipStream_t stream) {
    const float* x  = (const float*)d_in[0];
    const float* Wq = (const float*)d_in[1];
    const float* Wk = (const float*)d_in[2];
    const float* Wv = (const float*)d_in[3];
    const float* Wp = (const float*)d_in[4];
    const float* bp = (const float*)d_in[5];
    float* out = (float*)d_out;

    char* ws = (char*)d_ws;
    unsigned short* x_bf  = (unsigned short*)(ws);                           // 8 MB
    unsigned short* Wt    = (unsigned short*)(ws + ((size_t)8  << 20));      // 6 MB
    unsigned short* Wp_bf = (unsigned short*)(ws + ((size_t)14 << 20));      // 2 MB
    unsigned short* q_nat = (unsigned short*)(ws + ((size_t)16 << 20));      // 8 MB
    unsigned short* k_nat = (unsigned short*)(ws + ((size_t)24 << 20));      // 8 MB
    unsigned short* vT    = (unsigned short*)(ws + ((size_t)32 << 20));      // 8 MB
    unsigned short* y_bf  = (unsigned short*)(ws + ((size_t)40 << 20));      // 8 MB

    k_cvt<<<4096, 256, 0, stream>>>(x, x_bf, 4194304 / 4);
    k_cvt<<<1024, 256, 0, stream>>>(Wp, Wp_bf, 1048576 / 4);
    k_cvt_wt<<<768, 256, 0, stream>>>(Wq, Wk, Wv, Wt);
    k_gemm<0><<<24 * 32, 256, 0, stream>>>(x_bf, Wt, 4096, 3072, 1024,
                                           q_nat, k_nat, vT, nullptr, nullptr);
    k_attn<<<512, 256, 0, stream>>>(q_nat, k_nat, vT, y_bf);
    k_gemm<1><<<8 * 32, 256, 0, stream>>>(y_bf, Wp_bf, 4096, 1024, 1024,
                                          nullptr, nullptr, nullptr, out, bp);
}